// Round 7
// baseline (265.606 us; speedup 1.0000x reference)
//
#include <hip/hip_runtime.h>
#include <math.h>

// Problem constants (from reference): S=7, NB=2, C=20
#define SS 7
#define CC 20
#define CELL_PRED 30            // C + NB*5
#define CELL_TGT  25            // C + 1 + 4
#define BLOCK 256
// R6 lesson (quantified): scalar/float2 per-cell loads at 100/120B stride put
// each wave-instruction's 64 lanes on 64 distinct cache lines -> 40 line-
// transactions/cell -> 32M total -> ~52us of TA/L1 time. Warm-L3 replays run
// identical to cold (latency/HBM irrelevant) -> transaction-throughput bound.
// R7: one thread = 4 consecutive cells. Slabs: pred 480B, tgt 400B -- both
// 16B-aligned -> ALL loads are dwordx4 -> 15 transactions/cell (2.7x fewer).
// Keep R6's proven shape: no barriers, no LDS staging, partials + 2nd kernel.

__global__ __launch_bounds__(BLOCK, 3) void yolo_stream4(
    const float* __restrict__ pred,
    const float* __restrict__ tgt,
    float* __restrict__ partials,     // [gridDim.x]
    int nQuads)
{
    const float EPS = 1e-6f;
    const int tid = threadIdx.x;
    const int q = blockIdx.x * BLOCK + tid;

    float loss = 0.0f;
    if (q < nQuads) {
        const float4* p4 = (const float4*)pred + (size_t)q * (CELL_PRED);  // 30 f4
        const float4* t4 = (const float4*)tgt  + (size_t)q * (CELL_TGT);   // 25 f4

        #pragma unroll
        for (int k = 0; k < 4; ++k) {
            // pred words [30k, 30k+30): f4 [7.5k ..], word offset 30k&3
            const int pf = (30 * k) >> 2, po = (30 * k) & 3;   // {0,7,15,22},{0,2,0,2}
            // tgt words [25k, 25k+25): f4 [6.25k ..], word offset 25k&3
            const int tf = (25 * k) >> 2, to = (25 * k) & 3;   // {0,6,12,18},{0,1,2,3}

            float pw[32], tw[28];
            #pragma unroll
            for (int j = 0; j < 8; ++j) {                      // 8 pred f4
                float4 v = p4[pf + j];
                pw[4 * j] = v.x; pw[4 * j + 1] = v.y;
                pw[4 * j + 2] = v.z; pw[4 * j + 3] = v.w;
            }
            #pragma unroll
            for (int j = 0; j < 7; ++j) {                      // 7 tgt f4
                float4 v = t4[tf + j];
                tw[4 * j] = v.x; tw[4 * j + 1] = v.y;
                tw[4 * j + 2] = v.z; tw[4 * j + 3] = v.w;
            }
            const float* p = pw + po;   // p[0..29], static indices after unroll
            const float* t = tw + to;   // t[0..24]

            const float* b1 = p + CC;
            const float* b2 = p + CC + 5;
            const float* tb = t + CC;

            float obj = (tb[0] == 1.0f) ? 1.0f : 0.0f;

            float t_x1 = tb[0] - tb[2] * 0.5f, t_y1 = tb[1] - tb[3] * 0.5f;
            float t_x2 = tb[0] + tb[2] * 0.5f, t_y2 = tb[1] + tb[3] * 0.5f;
            float t_area = fabsf((t_x2 - t_x1) * (t_y2 - t_y1));

            float a_x1 = b1[0] - b1[2] * 0.5f, a_y1 = b1[1] - b1[3] * 0.5f;
            float a_x2 = b1[0] + b1[2] * 0.5f, a_y2 = b1[1] + b1[3] * 0.5f;
            float iw1 = fmaxf(fminf(a_x2, t_x2) - fmaxf(a_x1, t_x1), 0.0f);
            float ih1 = fmaxf(fminf(a_y2, t_y2) - fmaxf(a_y1, t_y1), 0.0f);
            float inter1 = iw1 * ih1;
            float area1 = fabsf((a_x2 - a_x1) * (a_y2 - a_y1));
            float iou1 = inter1 / (area1 + t_area - inter1 + EPS);

            float c_x1 = b2[0] - b2[2] * 0.5f, c_y1 = b2[1] - b2[3] * 0.5f;
            float c_x2 = b2[0] + b2[2] * 0.5f, c_y2 = b2[1] + b2[3] * 0.5f;
            float iw2 = fmaxf(fminf(c_x2, t_x2) - fmaxf(c_x1, t_x1), 0.0f);
            float ih2 = fmaxf(fminf(c_y2, t_y2) - fmaxf(c_y1, t_y1), 0.0f);
            float inter2 = iw2 * ih2;
            float area2 = fabsf((c_x2 - c_x1) * (c_y2 - c_y1));
            float iou2 = inter2 / (area2 + t_area - inter2 + EPS);

            bool pick1 = iou1 > iou2;
            float r0 = pick1 ? b1[0] : b2[0];
            float r1 = pick1 ? b1[1] : b2[1];
            float r2 = pick1 ? b1[2] : b2[2];
            float r3 = pick1 ? b1[3] : b2[3];
            float r4 = pick1 ? b1[4] : b2[4];

            float dx = r0 - tb[0], dy = r1 - tb[1];
            float xy = dx * dx + dy * dy;
            float dw = sqrtf(r2) - sqrtf(tb[2]);
            float dh = sqrtf(r3) - sqrtf(tb[3]);
            float wh = dw * dw + dh * dh;
            float coord = 5.0f * (xy + wh);
            float dconf = r4 - tb[4];
            float conf = dconf * dconf;

            float cls = 0.0f;
            #pragma unroll
            for (int kk = 0; kk < CC; ++kk) {
                float d = p[kk] - t[kk];
                cls += d * d;
            }

            float noobj = 0.5f * (1.0f - obj) * (b1[4] * b1[4] + b2[4] * b2[4]);
            loss += obj * (coord + conf + cls) + noobj;
        }
    }

    // wave butterfly, then 4 waves via tiny LDS
    #pragma unroll
    for (int off = 32; off > 0; off >>= 1)
        loss += __shfl_down(loss, off, 64);
    __shared__ float s_red[4];
    if ((tid & 63) == 0) s_red[tid >> 6] = loss;
    __syncthreads();
    if (tid == 0)
        partials[blockIdx.x] = (s_red[0] + s_red[1]) + (s_red[2] + s_red[3]);
}

__global__ __launch_bounds__(BLOCK) void yolo_final_reduce(
    const float* __restrict__ partials, int nPartials, double invN,
    float* __restrict__ out)
{
    __shared__ double s_red[4];
    const float4* p4 = (const float4*)partials;   // d_ws is 16-aligned
    double sum = 0.0;
    for (int i = threadIdx.x; i < (nPartials >> 2); i += BLOCK) {
        float4 v = p4[i];
        sum += (double)v.x + (double)v.y + (double)v.z + (double)v.w;
    }
    for (int i = ((nPartials >> 2) << 2) + threadIdx.x; i < nPartials; i += BLOCK)
        sum += (double)partials[i];
    #pragma unroll
    for (int off = 32; off > 0; off >>= 1)
        sum += __shfl_down(sum, off, 64);
    if ((threadIdx.x & 63) == 0) s_red[threadIdx.x >> 6] = sum;
    __syncthreads();
    if (threadIdx.x == 0) {
        double s = (s_red[0] + s_red[1]) + (s_red[2] + s_red[3]);
        out[0] = (float)(s * invN);
    }
}

extern "C" void kernel_launch(void* const* d_in, const int* in_sizes, int n_in,
                              void* d_out, int out_size, void* d_ws, size_t ws_size,
                              hipStream_t stream) {
    const float* pred = (const float*)d_in[0];
    const float* tgt  = (const float*)d_in[1];
    float* out = (float*)d_out;
    float* partials = (float*)d_ws;

    const int N = in_sizes[0] / (SS * SS * CELL_PRED);   // 16384
    const int nCells = N * SS * SS;                      // 802816 = 4 * 200704
    const int nQuads = nCells / 4;                       // 200704 = 784 * 256
    const int grid = (nQuads + BLOCK - 1) / BLOCK;       // 784, one-shot

    yolo_stream4<<<grid, BLOCK, 0, stream>>>(pred, tgt, partials, nQuads);
    yolo_final_reduce<<<1, BLOCK, 0, stream>>>(partials, grid, 1.0 / (double)N, out);
}

// Round 8
// 240.704 us; speedup vs baseline: 1.1035x; 1.1035x over previous
//
#include <hip/hip_runtime.h>
#include <math.h>

// Problem constants (from reference): S=7, NB=2, C=20
#define SS 7
#define CC 20
#define CELL_PRED 30            // C + NB*5
#define CELL_TGT  25            // C + 1 + 4
#define BLOCK 256
#define GRID 1024               // persistent: 4096 waves total, no WG churn
// R7 lesson: 480B/thread slabs via dwordx4 -> per-wave burst ~55KB thrashes
// L1 (32KB) and per-XCD L2 (4MB) -> every 64B line fetched ~4x from HBM
// (FETCH 378MB, 4.3x ideal) -> 136us. Slab-width vs fetch-amp law:
// 120B/f2 -> 1.28x (R6, good); 480B/f4 -> 4.3x (R7, poison).
// R6 cost fits TA line-throughput: 40 lines/cell -> 32M lines -> ~52us floor.
// R8: thread owns a PAIR of cells. pred keeps R6's proven f2 pattern
// (15 lines/cell); tgt pair-slab = 200B = 25 float2, 8-aligned for EVERY pair
// -> 12.5 lines/cell (was 25 scalar). Total 27.5 vs 40 lines/cell.

__device__ __forceinline__ float cell_loss_f2(const float2* __restrict__ p2,
                                              const float* __restrict__ tw) {
    const float EPS = 1e-6f;
    // pred: 15 float2 (120B, 8-aligned for every cell). Class part consumed
    // on the fly; tw[0..24] is in registers (static indices after unroll).
    float cls = 0.0f;
    #pragma unroll
    for (int j = 0; j < 10; ++j) {
        float2 v = p2[j];
        float d0 = v.x - tw[2 * j];
        float d1 = v.y - tw[2 * j + 1];
        cls += d0 * d0;
        cls += d1 * d1;
    }
    float b[10];
    #pragma unroll
    for (int j = 0; j < 5; ++j) {
        float2 v = p2[10 + j];
        b[2 * j] = v.x; b[2 * j + 1] = v.y;
    }
    const float* b1 = b;         // pred[20..24]
    const float* b2 = b + 5;     // pred[25..29]
    const float* tb = tw + CC;   // tgt[20..24]

    float obj = (tb[0] == 1.0f) ? 1.0f : 0.0f;

    float t_x1 = tb[0] - tb[2] * 0.5f, t_y1 = tb[1] - tb[3] * 0.5f;
    float t_x2 = tb[0] + tb[2] * 0.5f, t_y2 = tb[1] + tb[3] * 0.5f;
    float t_area = fabsf((t_x2 - t_x1) * (t_y2 - t_y1));

    float a_x1 = b1[0] - b1[2] * 0.5f, a_y1 = b1[1] - b1[3] * 0.5f;
    float a_x2 = b1[0] + b1[2] * 0.5f, a_y2 = b1[1] + b1[3] * 0.5f;
    float iw1 = fmaxf(fminf(a_x2, t_x2) - fmaxf(a_x1, t_x1), 0.0f);
    float ih1 = fmaxf(fminf(a_y2, t_y2) - fmaxf(a_y1, t_y1), 0.0f);
    float inter1 = iw1 * ih1;
    float area1 = fabsf((a_x2 - a_x1) * (a_y2 - a_y1));
    float iou1 = inter1 / (area1 + t_area - inter1 + EPS);

    float c_x1 = b2[0] - b2[2] * 0.5f, c_y1 = b2[1] - b2[3] * 0.5f;
    float c_x2 = b2[0] + b2[2] * 0.5f, c_y2 = b2[1] + b2[3] * 0.5f;
    float iw2 = fmaxf(fminf(c_x2, t_x2) - fmaxf(c_x1, t_x1), 0.0f);
    float ih2 = fmaxf(fminf(c_y2, t_y2) - fmaxf(c_y1, t_y1), 0.0f);
    float inter2 = iw2 * ih2;
    float area2 = fabsf((c_x2 - c_x1) * (c_y2 - c_y1));
    float iou2 = inter2 / (area2 + t_area - inter2 + EPS);

    bool pick1 = iou1 > iou2;
    float r0 = pick1 ? b1[0] : b2[0];
    float r1 = pick1 ? b1[1] : b2[1];
    float r2 = pick1 ? b1[2] : b2[2];
    float r3 = pick1 ? b1[3] : b2[3];
    float r4 = pick1 ? b1[4] : b2[4];

    float dx = r0 - tb[0], dy = r1 - tb[1];
    float xy = dx * dx + dy * dy;
    float dw = sqrtf(r2) - sqrtf(tb[2]);
    float dh = sqrtf(r3) - sqrtf(tb[3]);
    float wh = dw * dw + dh * dh;
    float coord = 5.0f * (xy + wh);
    float dconf = r4 - tb[4];
    float conf = dconf * dconf;

    float noobj = 0.5f * (1.0f - obj) * (b1[4] * b1[4] + b2[4] * b2[4]);
    return obj * (coord + conf + cls) + noobj;
}

__device__ __forceinline__ float pair_loss(const float* __restrict__ pred,
                                           const float* __restrict__ tgt,
                                           int p) {
    // tgt pair slab: 50 floats = 200B, 8-aligned for every pair -> 25 dwordx2
    const float2* t2 = (const float2*)(tgt + (size_t)p * (2 * CELL_TGT));
    // pred cell slabs: 30 floats = 120B, 8-aligned for every cell
    const float2* p2 = (const float2*)(pred + (size_t)p * (2 * CELL_PRED));

    // cell0: tgt words 0..24 (+word 25 rides along in tw0[25])
    float tw0[26];
    #pragma unroll
    for (int j = 0; j < 13; ++j) {
        float2 v = t2[j];
        tw0[2 * j] = v.x; tw0[2 * j + 1] = v.y;
    }
    float l = cell_loss_f2(p2, tw0);

    // cell1: tgt words 25..49 (word 25 already loaded)
    float tw1[25];
    tw1[0] = tw0[25];
    #pragma unroll
    for (int j = 0; j < 12; ++j) {
        float2 v = t2[13 + j];
        tw1[1 + 2 * j] = v.x; tw1[2 + 2 * j] = v.y;
    }
    l += cell_loss_f2(p2 + 15, tw1);
    return l;
}

__global__ __launch_bounds__(BLOCK) void yolo_pair(
    const float* __restrict__ pred,
    const float* __restrict__ tgt,
    float* __restrict__ partials,     // [GRID]
    int nPairs)
{
    const int tid = threadIdx.x;
    const int stride = GRID * BLOCK;  // 262144

    float loss = 0.0f;
    for (int p = blockIdx.x * BLOCK + tid; p < nPairs; p += stride)
        loss += pair_loss(pred, tgt, p);

    // wave butterfly, then 4 waves via tiny LDS
    #pragma unroll
    for (int off = 32; off > 0; off >>= 1)
        loss += __shfl_down(loss, off, 64);
    __shared__ float s_red[4];
    if ((tid & 63) == 0) s_red[tid >> 6] = loss;
    __syncthreads();
    if (tid == 0)
        partials[blockIdx.x] = (s_red[0] + s_red[1]) + (s_red[2] + s_red[3]);
}

__global__ __launch_bounds__(BLOCK) void yolo_final_reduce(
    const float* __restrict__ partials, int nPartials, double invN,
    float* __restrict__ out)
{
    __shared__ double s_red[4];
    const float4* p4 = (const float4*)partials;   // d_ws is 16-aligned
    double sum = 0.0;
    for (int i = threadIdx.x; i < (nPartials >> 2); i += BLOCK) {
        float4 v = p4[i];
        sum += (double)v.x + (double)v.y + (double)v.z + (double)v.w;
    }
    for (int i = ((nPartials >> 2) << 2) + threadIdx.x; i < nPartials; i += BLOCK)
        sum += (double)partials[i];
    #pragma unroll
    for (int off = 32; off > 0; off >>= 1)
        sum += __shfl_down(sum, off, 64);
    if ((threadIdx.x & 63) == 0) s_red[threadIdx.x >> 6] = sum;
    __syncthreads();
    if (threadIdx.x == 0) {
        double s = (s_red[0] + s_red[1]) + (s_red[2] + s_red[3]);
        out[0] = (float)(s * invN);
    }
}

extern "C" void kernel_launch(void* const* d_in, const int* in_sizes, int n_in,
                              void* d_out, int out_size, void* d_ws, size_t ws_size,
                              hipStream_t stream) {
    const float* pred = (const float*)d_in[0];
    const float* tgt  = (const float*)d_in[1];
    float* out = (float*)d_out;
    float* partials = (float*)d_ws;

    const int N = in_sizes[0] / (SS * SS * CELL_PRED);   // 16384
    const int nCells = N * SS * SS;                      // 802816
    const int nPairs = nCells / 2;                       // 401408

    yolo_pair<<<GRID, BLOCK, 0, stream>>>(pred, tgt, partials, nPairs);
    yolo_final_reduce<<<1, BLOCK, 0, stream>>>(partials, GRID, 1.0 / (double)N, out);
}